// Round 1
// baseline (492.547 us; speedup 1.0000x reference)
//
#include <hip/hip_runtime.h>

// WelfordEstimator: sequential Welford over batch dim B=32, per (s,h) position.
// x: (32, 2048, 1024) fp32. State: (2048,1024) mean/m2 fp32, nonzero int32, n scalar int.
// Output layout (all read back as fp32 by harness):
//   [0, B*SH)          : x passthrough
//   [B*SH, B*SH+SH)    : mean
//   [+SH, +2SH)        : m2
//   [+2SH, +3SH)       : nonzero (as float value — counts <= 32+n0, exact in fp32)
//   [B*SH+3SH]         : num_samples (as float value)

#define BATCH 32
#define SH (2048LL * 1024LL)   // 2,097,152 positions

__global__ __launch_bounds__(256) void welford_kernel(
    const float* __restrict__ x,
    const float* __restrict__ mean_in,
    const float* __restrict__ m2_in,
    const int*   __restrict__ nz_in,
    const int*   __restrict__ n_in,
    float* __restrict__ out)
{
    const long long tid = (long long)blockIdx.x * blockDim.x + threadIdx.x;
    const long long pos = tid * 4;          // 4 consecutive positions per thread
    if (pos >= SH) return;

    float4 mean = *(const float4*)(mean_in + pos);
    float4 m2   = *(const float4*)(m2_in   + pos);
    int4   nz   = *(const int4*)  (nz_in   + pos);
    const int n0 = *n_in;

    float* __restrict__ out_x    = out;
    float* __restrict__ out_mean = out + (long long)BATCH * SH;
    float* __restrict__ out_m2   = out_mean + SH;
    float* __restrict__ out_nz   = out_m2 + SH;

    #pragma unroll 4
    for (int b = 0; b < BATCH; ++b) {
        const long long off = (long long)b * SH + pos;
        const float4 xv = *(const float4*)(x + off);
        *(float4*)(out_x + off) = xv;       // fused passthrough copy: x read exactly once

        // one division per step, shared across the 4 lanes of this thread
        const float inv = 1.0f / (float)(n0 + b + 1);

        {
            nz.x += (xv.x != 0.0f);
            const float d = xv.x - mean.x;  // xi - old_mean
            mean.x += d * inv;
            m2.x += (xv.x - mean.x) * d;    // (xi - new_mean)*(xi - old_mean)
        }
        {
            nz.y += (xv.y != 0.0f);
            const float d = xv.y - mean.y;
            mean.y += d * inv;
            m2.y += (xv.y - mean.y) * d;
        }
        {
            nz.z += (xv.z != 0.0f);
            const float d = xv.z - mean.z;
            mean.z += d * inv;
            m2.z += (xv.z - mean.z) * d;
        }
        {
            nz.w += (xv.w != 0.0f);
            const float d = xv.w - mean.w;
            mean.w += d * inv;
            m2.w += (xv.w - mean.w) * d;
        }
    }

    *(float4*)(out_mean + pos) = mean;
    *(float4*)(out_m2   + pos) = m2;
    const float4 nzf = make_float4((float)nz.x, (float)nz.y, (float)nz.z, (float)nz.w);
    *(float4*)(out_nz   + pos) = nzf;

    if (tid == 0) {
        out[(long long)(BATCH + 3) * SH] = (float)(n0 + BATCH);  // num_samples
    }
}

extern "C" void kernel_launch(void* const* d_in, const int* in_sizes, int n_in,
                              void* d_out, int out_size, void* d_ws, size_t ws_size,
                              hipStream_t stream) {
    const float* x    = (const float*)d_in[0];
    const float* mean = (const float*)d_in[1];
    const float* m2   = (const float*)d_in[2];
    const int*   nz   = (const int*)d_in[3];
    const int*   nsmp = (const int*)d_in[4];
    float* out = (float*)d_out;

    const long long n_threads = SH / 4;           // 524,288
    const int block = 256;
    const int grid = (int)((n_threads + block - 1) / block);  // 2048 blocks

    welford_kernel<<<grid, block, 0, stream>>>(x, mean, m2, nz, nsmp, out);
}